// Round 14
// baseline (541.967 us; speedup 1.0000x reference)
//
#include <hip/hip_runtime.h>

typedef _Float16 HALF;
typedef _Float16 f16x8 __attribute__((ext_vector_type(8)));
typedef float f32x4 __attribute__((ext_vector_type(4)));
typedef int i32x4 __attribute__((ext_vector_type(4)));

// ---- fused weight conversion: fp32 (27*CI, CO) -> fp16 tiled [KP/32][CO_PAD][32], zero padded
struct WArgs { const float* W[8]; HALF* dst[8]; };

__global__ void convert_all_w_kernel(WArgs a)
{
    const int CIs[8]  = {64, 64, 64, 64, 32, 32, 16, 16};
    const int COs[8]  = {64, 64, 64, 32, 32, 16, 16, 3};
    const int COPs[8] = {64, 64, 64, 32, 32, 16, 16, 16};
    const int L = blockIdx.y;
    const int CI = CIs[L], CO = COs[L], COP = COPs[L];
    const int K = 27 * CI, KP = (K + 31) & ~31;
    const int total = COP * KP;
    for (int i = blockIdx.x * 256 + threadIdx.x; i < total; i += gridDim.x * 256) {
        int jp = i / KP;          // out channel (padded)
        int kp = i - jp * KP;     // k (padded)
        float v = (jp < CO && kp < K) ? a.W[L][(size_t)kp * CO + jp] : 0.f;
        a.dst[L][((size_t)(kp >> 5) * COP + jp) * 32 + (kp & 31)] = (HALF)v;
    }
}

__global__ void convert_x_kernel(const float* __restrict__ x, HALF* __restrict__ xh, int total)
{
    int i = blockIdx.x * 256 + threadIdx.x;
    if (i < total) xh[i] = (HALF)x[i];
}

// ================= conv_band: band-streaming CI=64 kernel (m4/i4/m3) =================
// The gather wall (r0-r13): conv64 pinned at ~9.3 cyc per scattered 64B segment,
// MSHR x latency bound. Exit: rows are KEY-SORTED, so for one (dz,dy) the 3 dx-tap
// indices of a 32-row block form a narrow CONTIGUOUS band. Load 9 bands streaming
// into LDS (double-buffered), serve all taps from LDS. 1728 scattered segs/block
// -> ~720 contiguous. Per-group fallback to direct gathers if band > BMAX rows.
// Wave layout: mt = wv&1 (16 rows), kh = wv>>1 (32-ch half); 2-way kh-reduction.
// Band rows padded to 144B (bank stride 4) -> conflict-light LDS reads.
template<int CO_PAD, bool FUSED>
__global__ __launch_bounds__(256, 2) void conv_band(
    const HALF* __restrict__ h, const int* __restrict__ nbr,
    const HALF* __restrict__ Wt, HALF* __restrict__ yout,
    float* __restrict__ sums, int n,
    const float* __restrict__ psums, const float* __restrict__ pg,
    const float* __restrict__ pb, float pinvn)
{
    constexpr int CI    = 64;
    constexpr int NJB   = CO_PAD / 16;
    constexpr int ROWS  = 32;
    constexpr int BMAX  = 128;                    // max band rows held in LDS
    constexpr int RPAD  = 72;                     // HALFs per band row (144B)

    __shared__ float lscbi[2][64];
    __shared__ int   lidx[ROWS * 27];
    __shared__ int   glo[9], ghi[9];
    __shared__ HALF  band[2][BMAX * RPAD];        // 2 x 18KB
    __shared__ f32x4 lred[2][NJB * 64];           // kh-partner reduction

    const int wv   = threadIdx.x >> 6;
    const int lane = threadIdx.x & 63;
    const int l15  = lane & 15;
    const int lq   = lane >> 4;
    const int mt   = wv & 1;                      // row tile
    const int kh   = wv >> 1;                     // channel half

    int bid = blockIdx.x;
    {
        const int nwg = gridDim.x;
        const int q = nwg >> 3, r = nwg & 7;
        const int xcd = bid & 7, idx = bid >> 3;
        bid = (xcd < r ? xcd * (q + 1) : r * (q + 1) + (xcd - r) * q) + idx;
    }
    const int rowBase = bid * ROWS;

    // ---- stage nbr slice (coalesced; OOB rows -> -1)
    for (int i = threadIdx.x; i < ROWS * 27; i += 256) {
        const int r   = i / 27;
        const int row = rowBase + r;
        lidx[i] = (row < n) ? nbr[(size_t)row * 27 + (i - r * 27)] : -1;
    }
    // ---- in-kernel bn_prep
    if constexpr (FUSED) {
        const int c = threadIdx.x;
        if (c < CI) {
            float s = 0.f, q = 0.f;
#pragma unroll
            for (int k = 0; k < 8; ++k) { s += psums[k * 128 + c]; q += psums[k * 128 + CI + c]; }
            const float mu  = s * pinvn;
            const float var = q * pinvn - mu * mu;
            const float sc  = rsqrtf(var + 1e-3f) * pg[c];
            lscbi[0][c] = sc;
            lscbi[1][c] = pb[c] - mu * sc;
        }
    }
    if (threadIdx.x < 9) { glo[threadIdx.x] = 0x7fffffff; ghi[threadIdx.x] = -1; }
    __syncthreads();

    // ---- per-(dz,dy)-group band bounds: 216 threads x 4 entries (96 = 32 rows x 3 dx)
    if (threadIdx.x < 216) {
        const int g = threadIdx.x / 24, j = threadIdx.x % 24;
        int mn = 0x7fffffff, mx = -1;
#pragma unroll
        for (int e = j * 4; e < j * 4 + 4; ++e) {
            const int r = e / 3, t = g * 3 + e % 3;
            const int v = lidx[r * 27 + t];
            if (v >= 0) { mn = min(mn, v); mx = max(mx, v); }
        }
        if (mx >= 0) { atomicMin(&glo[g], mn); atomicMax(&ghi[g], mx); }
    }
    __syncthreads();

    // per-wave bn constants (fixed kh)
    f16x8 sc8, bi8;
    if constexpr (FUSED) {
        const int c0 = kh * 32 + lq * 8;
#pragma unroll
        for (int j = 0; j < 8; ++j) { sc8[j] = (HALF)lscbi[0][c0 + j]; bi8[j] = (HALF)lscbi[1][c0 + j]; }
    }

    f32x4 acc[NJB];
#pragma unroll
    for (int jb = 0; jb < NJB; ++jb)
#pragma unroll
        for (int r = 0; r < 4; ++r) acc[jb][r] = 0.f;

    const int lbase = (mt * 16 + l15) * 27;       // lidx row base for my 16 rows

    #define LOADBAND(g_, buf_) do { \
        const int lo_ = glo[g_]; \
        const int W_  = ghi[g_] - lo_ + 1; \
        for (int u = threadIdx.x; u < W_ * 8; u += 256) { \
            const int rr_ = u >> 3, ck_ = u & 7; \
            const i32x4 v_ = *(const i32x4*)(h + (size_t)(lo_ + rr_) * 64 + ck_ * 8); \
            *(i32x4*)(&band[buf_][rr_ * RPAD + ck_ * 8]) = v_; \
        } \
    } while (0)

    #define CONSUME(aV_, imV_, bV_) do { \
        f16x8 a_ = (aV_); \
        if constexpr (FUSED) { \
            a_ = a_ * sc8 + bi8; \
            _Pragma("unroll") \
            for (int j_ = 0; j_ < 8; ++j_) a_[j_] = (a_[j_] < (HALF)0.f) ? (HALF)0.f : a_[j_]; \
        } \
        const int m_ = ~((imV_) >> 31); \
        i32x4 ai_ = __builtin_bit_cast(i32x4, a_); \
        ai_.x &= m_; ai_.y &= m_; ai_.z &= m_; ai_.w &= m_; \
        a_ = __builtin_bit_cast(f16x8, ai_); \
        _Pragma("unroll") \
        for (int jb_ = 0; jb_ < NJB; ++jb_) \
            acc[jb_] = __builtin_amdgcn_mfma_f32_16x16x32_f16(a_, (bV_)[jb_], acc[jb_], 0, 0, 0); \
    } while (0)

    // mode per group (uniform): 0 empty, 1 band, 2 fallback
    #define GMODE(g_) ((ghi[g_] < 0) ? 0 : ((ghi[g_] - glo[g_] + 1 <= BMAX) ? 1 : 2))

    if (GMODE(0) == 1) LOADBAND(0, 0);
    __syncthreads();

    for (int g = 0; g < 9; ++g) {
        if (g + 1 < 9 && GMODE(g + 1) == 1) LOADBAND(g + 1, (g + 1) & 1);

        const int gm = GMODE(g);
        if (gm == 1) {
            const int lo = glo[g];
            const HALF* bb = &band[g & 1][0];
#pragma unroll
            for (int dxi = 0; dxi < 3; ++dxi) {
                const int t   = g * 3 + dxi;
                const int idx = lidx[lbase + t];
                const int off = max(idx, lo) - lo;
                const f16x8 a = *(const f16x8*)(bb + off * RPAD + kh * 32 + lq * 8);

                const HALF* wb = Wt + (size_t)(2 * t + kh) * (CO_PAD * 32) + lq * 8;
                f16x8 b[NJB];
#pragma unroll
                for (int jb = 0; jb < NJB; ++jb)
                    b[jb] = *(const f16x8*)(wb + (size_t)(jb * 16 + l15) * 32);

                CONSUME(a, idx, b);
            }
        } else if (gm == 2) {
#pragma unroll
            for (int dxi = 0; dxi < 3; ++dxi) {
                const int t   = g * 3 + dxi;
                const int idx = lidx[lbase + t];
                const f16x8 a = *(const f16x8*)(h + ((size_t)max(idx, 0) << 6) + kh * 32 + lq * 8);

                const HALF* wb = Wt + (size_t)(2 * t + kh) * (CO_PAD * 32) + lq * 8;
                f16x8 b[NJB];
#pragma unroll
                for (int jb = 0; jb < NJB; ++jb)
                    b[jb] = *(const f16x8*)(wb + (size_t)(jb * 16 + l15) * 32);

                CONSUME(a, idx, b);
            }
        }
        __syncthreads();
    }
    #undef GMODE
    #undef CONSUME
    #undef LOADBAND

    // ---- kh-partner reduction: waves 2,3 -> lred[mt]; waves 0,1 add + epilogue
    if (kh == 1) {
#pragma unroll
        for (int jb = 0; jb < NJB; ++jb)
            lred[mt][jb * 64 + lane] = acc[jb];
    }
    __syncthreads();
    if (kh == 0) {
#pragma unroll
        for (int jb = 0; jb < NJB; ++jb)
            acc[jb] += lred[mt][jb * 64 + lane];

        // epilogue: store RAW pre-norm y + striped stats (this wave's 16 rows)
        float* sl = sums + (bid & 7) * 128;
#pragma unroll
        for (int jb = 0; jb < NJB; ++jb) {
            const int col = jb * 16 + l15;
            float s = 0.f, sq = 0.f;
            const int rb = rowBase + mt * 16 + lq * 4;
#pragma unroll
            for (int r = 0; r < 4; ++r) {
                if (rb + r < n) {
                    const float v = acc[jb][r];
                    yout[(size_t)(rb + r) * CO_PAD + col] = (HALF)v;
                    s += v;
                    sq += v * v;
                }
            }
            s  += __shfl_xor(s, 16);  s  += __shfl_xor(s, 32);
            sq += __shfl_xor(sq, 16); sq += __shfl_xor(sq, 32);
            if (lane < 16) {
                atomicAdd(&sl[col], s);
                atomicAdd(&sl[CO_PAD + col], sq);
            }
        }
    }
}

// ================= conv_dyn: compact-active-tap kernel (sparse layers) =================
template<int CI, int CO_PAD, bool FUSED>
__global__ __launch_bounds__(256, 2) void conv_dyn(
    const HALF* __restrict__ h, const int* __restrict__ nbr,
    const HALF* __restrict__ Wt, HALF* __restrict__ yout,
    float* __restrict__ sums, int n,
    const float* __restrict__ psums, const float* __restrict__ pg,
    const float* __restrict__ pb, float pinvn)
{
    constexpr int NMT   = 2;
    constexpr int NJB   = CO_PAD / 16;
    constexpr int NCB   = (CI >= 64) ? 2 : 1;
    constexpr int ROWS  = 32;
    constexpr int PAIRS = NMT * NJB;

    __shared__ f32x4 lred[2][PAIRS * 64];
    __shared__ float lscbi[2][64];
    __shared__ int   lidx[ROWS * 27];
    __shared__ int   tflag[27];
    __shared__ int   tls[32];
    __shared__ int   ntapS;

    const int wv   = threadIdx.x >> 6;
    const int lane = threadIdx.x & 63;
    const int l15  = lane & 15;
    const int lq   = lane >> 4;

    int bid = blockIdx.x;
    {
        const int nwg = gridDim.x;
        const int q = nwg >> 3, r = nwg & 7;
        const int xcd = bid & 7, idx = bid >> 3;
        bid = (xcd < r ? xcd * (q + 1) : r * (q + 1) + (xcd - r) * q) + idx;
    }
    const int rowBase = bid * ROWS;

    for (int i = threadIdx.x; i < ROWS * 27; i += 256) {
        const int r   = i / 27;
        const int row = rowBase + r;
        lidx[i] = (row < n) ? nbr[(size_t)row * 27 + (i - r * 27)] : -1;
    }
    if constexpr (FUSED) {
        const int c = threadIdx.x;
        if (c < CI) {
            float s = 0.f, q = 0.f;
#pragma unroll
            for (int k = 0; k < 8; ++k) { s += psums[k * 128 + c]; q += psums[k * 128 + CI + c]; }
            const float mu  = s * pinvn;
            const float var = q * pinvn - mu * mu;
            const float sc  = rsqrtf(var + 1e-3f) * pg[c];
            lscbi[0][c] = sc;
            lscbi[1][c] = pb[c] - mu * sc;
        }
    }
    __syncthreads();

    if (threadIdx.x < 27) {
        int any = 0;
        for (int r = 0; r < ROWS; ++r) any |= ~(lidx[r * 27 + threadIdx.x] >> 31);
        tflag[threadIdx.x] = any & 1;
    }
    __syncthreads();
    if (threadIdx.x == 0) {
        int c = 0;
#pragma unroll
        for (int t = 0; t < 27; ++t) if (tflag[t]) tls[c++] = t;
        ntapS = c;
        for (int t = c; t < 32; ++t) tls[t] = 27;  // sentinel pad
    }
    __syncthreads();
    const int NT = ntapS;

    f16x8 sc8[NCB], bi8[NCB];
    if constexpr (FUSED) {
#pragma unroll
        for (int cb = 0; cb < NCB; ++cb) {
            const int c0 = cb * 32 + ((lq * 8) & (CI - 1));
#pragma unroll
            for (int j = 0; j < 8; ++j) {
                sc8[cb][j] = (HALF)lscbi[0][c0 + j];
                bi8[cb][j] = (HALF)lscbi[1][c0 + j];
            }
        }
    }

    f32x4 acc[NMT][NJB];
#pragma unroll
    for (int mt = 0; mt < NMT; ++mt)
#pragma unroll
        for (int jb = 0; jb < NJB; ++jb)
#pragma unroll
            for (int r = 0; r < 4; ++r) acc[mt][jb][r] = 0.f;

    int lb[NMT];
#pragma unroll
    for (int mt = 0; mt < NMT; ++mt) lb[mt] = (mt * 16 + l15) * 27;

    #define CONSUME(aV_, imV_, bV_, CBIDX_) do { \
        f16x8 a_ = (aV_); \
        if constexpr (FUSED) { \
            a_ = a_ * sc8[CBIDX_] + bi8[CBIDX_]; \
            _Pragma("unroll") \
            for (int j_ = 0; j_ < 8; ++j_) a_[j_] = (a_[j_] < (HALF)0.f) ? (HALF)0.f : a_[j_]; \
        } \
        const int m_ = ~((imV_) >> 31); \
        i32x4 ai_ = __builtin_bit_cast(i32x4, a_); \
        ai_.x &= m_; ai_.y &= m_; ai_.z &= m_; ai_.w &= m_; \
        a_ = __builtin_bit_cast(f16x8, ai_); \
        _Pragma("unroll") \
        for (int jb_ = 0; jb_ < NJB; ++jb_) \
            acc[mt][jb_] = __builtin_amdgcn_mfma_f32_16x16x32_f16(a_, (bV_)[jb_], acc[mt][jb_], 0, 0, 0); \
    } while (0)

    if constexpr (CI == 64) {
        int ti = wv;
        int   tcur, icur[NMT];
        f16x8 a0c[NMT], a1c[NMT];
        {
            tcur = tls[ti];
#pragma unroll
            for (int mt = 0; mt < NMT; ++mt) {
                const int idx = (tcur < 27) ? lidx[lb[mt] + min(tcur, 26)] : -1;
                icur[mt] = idx;
                const HALF* pa = h + ((max(idx, 0) << 6) + lq * 8);
                a0c[mt] = *(const f16x8*)(pa);
                a1c[mt] = *(const f16x8*)(pa + 32);
            }
        }
        for (; ti < NT; ti += 4) {
            int   tnx = tls[min(ti + 4, 31)];
            int   inx[NMT];
            f16x8 a0n[NMT], a1n[NMT];
#pragma unroll
            for (int mt = 0; mt < NMT; ++mt) {
                const int idx = (tnx < 27) ? lidx[lb[mt] + min(tnx, 26)] : -1;
                inx[mt] = idx;
                const HALF* pa = h + ((max(idx, 0) << 6) + lq * 8);
                a0n[mt] = *(const f16x8*)(pa);
                a1n[mt] = *(const f16x8*)(pa + 32);
            }

            const HALF* wb = Wt + (size_t)(2 * tcur) * (CO_PAD * 32) + lq * 8;
            f16x8 b0[NJB], b1[NJB];
#pragma unroll
            for (int jb = 0; jb < NJB; ++jb) {
                b0[jb] = *(const f16x8*)(wb + (size_t)(jb * 16 + l15) * 32);
                b1[jb] = *(const f16x8*)(wb + CO_PAD * 32 + (size_t)(jb * 16 + l15) * 32);
            }

#pragma unroll
            for (int mt = 0; mt < NMT; ++mt) CONSUME(a0c[mt], icur[mt], b0, 0);
#pragma unroll
            for (int mt = 0; mt < NMT; ++mt) CONSUME(a1c[mt], icur[mt], b1, NCB - 1);

            tcur = tnx;
#pragma unroll
            for (int mt = 0; mt < NMT; ++mt) {
                icur[mt] = inx[mt]; a0c[mt] = a0n[mt]; a1c[mt] = a1n[mt];
            }
        }
    } else if constexpr (CI == 32) {
        int ti = wv;
        int   tcur, icur[NMT];
        f16x8 ac[NMT];
        {
            tcur = tls[ti];
#pragma unroll
            for (int mt = 0; mt < NMT; ++mt) {
                const int idx = (tcur < 27) ? lidx[lb[mt] + min(tcur, 26)] : -1;
                icur[mt] = idx;
                ac[mt] = *(const f16x8*)(h + ((max(idx, 0) << 5) + lq * 8));
            }
        }
        for (; ti < NT; ti += 4) {
            int   tnx = tls[min(ti + 4, 31)];
            int   inx[NMT];
            f16x8 an[NMT];
#pragma unroll
            for (int mt = 0; mt < NMT; ++mt) {
                const int idx = (tnx < 27) ? lidx[lb[mt] + min(tnx, 26)] : -1;
                inx[mt] = idx;
                an[mt] = *(const f16x8*)(h + ((max(idx, 0) << 5) + lq * 8));
            }

            const HALF* wb = Wt + (size_t)tcur * (CO_PAD * 32) + lq * 8;
            f16x8 b[NJB];
#pragma unroll
            for (int jb = 0; jb < NJB; ++jb)
                b[jb] = *(const f16x8*)(wb + (size_t)(jb * 16 + l15) * 32);

#pragma unroll
            for (int mt = 0; mt < NMT; ++mt) CONSUME(ac[mt], icur[mt], b, 0);

            tcur = tnx;
#pragma unroll
            for (int mt = 0; mt < NMT; ++mt) { icur[mt] = inx[mt]; ac[mt] = an[mt]; }
        }
    } else {
        // CI == 16: two list entries per MFMA step (lq>>1 selects); sentinel masked
        const int NS = (NT + 1) >> 1;
        int ti = wv;
        int   tcur, icur[NMT];
        f16x8 ac[NMT];
        {
            tcur = tls[min(2 * ti + (lq >> 1), 31)];
#pragma unroll
            for (int mt = 0; mt < NMT; ++mt) {
                const int idx = (tcur < 27) ? lidx[lb[mt] + min(tcur, 26)] : -1;
                icur[mt] = idx;
                ac[mt] = *(const f16x8*)(h + ((max(idx, 0) << 4) + (lq & 1) * 8));
            }
        }
        for (; ti < NS; ti += 4) {
            int   tnx = tls[min(2 * (ti + 4) + (lq >> 1), 31)];
            int   inx[NMT];
            f16x8 an[NMT];
#pragma unroll
            for (int mt = 0; mt < NMT; ++mt) {
                const int idx = (tnx < 27) ? lidx[lb[mt] + min(tnx, 26)] : -1;
                inx[mt] = idx;
                an[mt] = *(const f16x8*)(h + ((max(idx, 0) << 4) + (lq & 1) * 8));
            }

            const int tb = min(tcur, 26);
            f16x8 b[NJB];
#pragma unroll
            for (int jb = 0; jb < NJB; ++jb)
                b[jb] = *(const f16x8*)(Wt + (size_t)(tb >> 1) * (CO_PAD * 32)
                                        + (size_t)(jb * 16 + l15) * 32 + (tb & 1) * 16 + (lq & 1) * 8);

#pragma unroll
            for (int mt = 0; mt < NMT; ++mt) CONSUME(ac[mt], icur[mt], b, 0);

            tcur = tnx;
#pragma unroll
            for (int mt = 0; mt < NMT; ++mt) { icur[mt] = inx[mt]; ac[mt] = an[mt]; }
        }
    }
    #undef CONSUME

    // ---- cross-wave tree reduction (3 syncs)
    if (wv & 1) {
#pragma unroll
        for (int mt = 0; mt < NMT; ++mt)
#pragma unroll
            for (int jb = 0; jb < NJB; ++jb)
                lred[wv >> 1][(mt * NJB + jb) * 64 + lane] = acc[mt][jb];
    }
    __syncthreads();
    if (!(wv & 1)) {
#pragma unroll
        for (int mt = 0; mt < NMT; ++mt)
#pragma unroll
            for (int jb = 0; jb < NJB; ++jb)
                acc[mt][jb] += lred[wv >> 1][(mt * NJB + jb) * 64 + lane];
    }
    __syncthreads();
    if (wv == 2) {
#pragma unroll
        for (int mt = 0; mt < NMT; ++mt)
#pragma unroll
            for (int jb = 0; jb < NJB; ++jb)
                lred[0][(mt * NJB + jb) * 64 + lane] = acc[mt][jb];
    }
    __syncthreads();

    if (wv == 0) {
#pragma unroll
        for (int mt = 0; mt < NMT; ++mt)
#pragma unroll
            for (int jb = 0; jb < NJB; ++jb)
                acc[mt][jb] += lred[0][(mt * NJB + jb) * 64 + lane];

        float* sl = sums + (bid & 7) * 128;
#pragma unroll
        for (int jb = 0; jb < NJB; ++jb) {
            const int col = jb * 16 + l15;
            float s = 0.f, sq = 0.f;
#pragma unroll
            for (int mt = 0; mt < NMT; ++mt) {
                const int rb = rowBase + mt * 16 + lq * 4;
#pragma unroll
                for (int r = 0; r < 4; ++r) {
                    if (rb + r < n) {
                        const float v = acc[mt][jb][r];
                        yout[(size_t)(rb + r) * CO_PAD + col] = (HALF)v;
                        s += v;
                        sq += v * v;
                    }
                }
            }
            s  += __shfl_xor(s, 16);  s  += __shfl_xor(s, 32);
            sq += __shfl_xor(sq, 16); sq += __shfl_xor(sq, 32);
            if (lane < 16) {
                atomicAdd(&sl[col], s);
                atomicAdd(&sl[CO_PAD + col], sq);
            }
        }
    }
}

// ---- final: normalize (no relu), co=3 out of CO_PAD=16, fp32 output; striped sums
__global__ void bn_out_kernel(const HALF* __restrict__ y, const float* __restrict__ sums,
                              const float* __restrict__ g, const float* __restrict__ b,
                              int n, float invn, float* __restrict__ out)
{
    int i = blockIdx.x * 256 + threadIdx.x;
    if (i >= n * 3) return;
    int row = i / 3;
    int c = i - row * 3;
    float ssum = 0.f, qsum = 0.f;
#pragma unroll
    for (int k2 = 0; k2 < 8; ++k2) {
        ssum += sums[k2 * 128 + c];
        qsum += sums[k2 * 128 + 16 + c];
    }
    float mu  = ssum * invn;
    float var = qsum * invn - mu * mu;
    float sc  = rsqrtf(var + 1e-3f) * g[c];
    out[i] = ((float)y[(size_t)row * 16 + c] - mu) * sc + b[c];
}

extern "C" void kernel_launch(void* const* d_in, const int* in_sizes, int n_in,
                              void* d_out, int out_size, void* d_ws, size_t ws_size,
                              hipStream_t stream)
{
    const int* nbr4  = (const int*)d_in[0];
    const int* inv43 = (const int*)d_in[1];
    const int* nbr3  = (const int*)d_in[2];
    const int* inv32 = (const int*)d_in[3];
    const int* nbr2  = (const int*)d_in[4];
    const int* inv21 = (const int*)d_in[5];
    const int* nbr1  = (const int*)d_in[6];
    const float* x   = (const float*)d_in[7];

    const int n4 = in_sizes[0] / 27;
    const int n3 = in_sizes[1] / 27;
    const int n2 = in_sizes[3] / 27;
    const int n1 = in_sizes[5] / 27;

    // specs: m4,i4,m3,i3,m2,i2,m1,c5
    const int CIs[8]  = {64, 64, 64, 64, 32, 32, 16, 16};
    const int COPs[8] = {64, 64, 64, 32, 32, 16, 16, 16};
    int KPs[8], wtoff[8];
    int wtot = 0;
    for (int s = 0; s < 8; ++s) {
        KPs[s] = ((27 * CIs[s] + 31) / 32) * 32;
        wtoff[s] = wtot;
        wtot += COPs[s] * KPs[s];
    }

    char* ws = (char*)d_ws;
    HALF* wt = (HALF*)ws;
    size_t off = ((size_t)wtot * sizeof(HALF) + 255) & ~(size_t)255;
    float* sums = (float*)(ws + off);
    off += 8 * 1024 * sizeof(float);              // 8 layers x 8 stripes x 128 floats
    off = (off + 255) & ~(size_t)255;
    HALF* xh = (HALF*)(ws + off);
    off += ((size_t)n4 * 64 * sizeof(HALF) + 255) & ~(size_t)255;
    size_t bufElems = 0;
    {
        size_t cand[4] = {(size_t)n4 * 64, (size_t)n3 * 64, (size_t)n2 * 32, (size_t)n1 * 16};
        for (int i = 0; i < 4; ++i) if (cand[i] > bufElems) bufElems = cand[i];
    }
    HALF* Y0 = (HALF*)(ws + off);
    off += (bufElems * sizeof(HALF) + 255) & ~(size_t)255;
    HALF* Y1 = (HALF*)(ws + off);

    hipMemsetAsync(sums, 0, 8 * 1024 * sizeof(float), stream);

    WArgs wa;
    for (int s = 0; s < 8; ++s) { wa.W[s] = (const float*)d_in[8 + 3 * s]; wa.dst[s] = wt + wtoff[s]; }
    {
        int maxTotal = 64 * KPs[0];
        dim3 grid((maxTotal + 255) / 256, 8);
        convert_all_w_kernel<<<grid, 256, 0, stream>>>(wa);
    }
    convert_x_kernel<<<(n4 * 64 + 255) / 256, 256, 0, stream>>>(x, xh, n4 * 64);

#define G(s) ((const float*)d_in[9 + 3 * (s)])
#define B(s) ((const float*)d_in[10 + 3 * (s)])
#define SUMS(s) (sums + (s) * 1024)
#define GRID(nn) (((nn) + 31) / 32)

    // m4: xh(n4,64) -> Y0 (raw)  [band-streaming]
    conv_band<64, false><<<GRID(n4), 256, 0, stream>>>(
        xh, nbr4, wt + wtoff[0], Y0, SUMS(0), n4, nullptr, nullptr, nullptr, 0.f);
    // i4: norm(m4) fused; Y0(n4) -> Y1(n3)  [band-streaming]
    conv_band<64, true><<<GRID(n3), 256, 0, stream>>>(
        Y0, inv43, wt + wtoff[1], Y1, SUMS(1), n3, SUMS(0), G(0), B(0), 1.f / n4);
    // m3: norm(i4) fused; Y1 -> Y0  [band-streaming]
    conv_band<64, true><<<GRID(n3), 256, 0, stream>>>(
        Y1, nbr3, wt + wtoff[2], Y0, SUMS(2), n3, SUMS(1), G(1), B(1), 1.f / n3);
    // i3: norm(m3) fused; Y0(n3) -> Y1(n2), co 32  [dynamic]
    conv_dyn<64, 32, true><<<GRID(n2), 256, 0, stream>>>(
        Y0, inv32, wt + wtoff[3], Y1, SUMS(3), n2, SUMS(2), G(2), B(2), 1.f / n3);
    // m2: norm(i3) fused; Y1 -> Y0  [dynamic]
    conv_dyn<32, 32, true><<<GRID(n2), 256, 0, stream>>>(
        Y1, nbr2, wt + wtoff[4], Y0, SUMS(4), n2, SUMS(3), G(3), B(3), 1.f / n2);
    // i2: norm(m2) fused; Y0(n2) -> Y1(n1), co 16  [dynamic]
    conv_dyn<32, 16, true><<<GRID(n1), 256, 0, stream>>>(
        Y0, inv21, wt + wtoff[5], Y1, SUMS(5), n1, SUMS(4), G(4), B(4), 1.f / n2);
    // m1: norm(i2) fused; Y1 -> Y0  [dynamic]
    conv_dyn<16, 16, true><<<GRID(n1), 256, 0, stream>>>(
        Y1, nbr1, wt + wtoff[6], Y0, SUMS(6), n1, SUMS(5), G(5), B(5), 1.f / n1);
    // c5: norm(m1) fused; Y0 -> Y1 (raw), then fp32 out  [dynamic]
    conv_dyn<16, 16, true><<<GRID(n1), 256, 0, stream>>>(
        Y0, nbr1, wt + wtoff[7], Y1, SUMS(7), n1, SUMS(6), G(6), B(6), 1.f / n1);
    bn_out_kernel<<<(n1 * 3 + 255) / 256, 256, 0, stream>>>(
        Y1, SUMS(7), G(7), B(7), n1, 1.f / n1, (float*)d_out);

#undef G
#undef B
#undef SUMS
#undef GRID
}

// Round 15
// 460.478 us; speedup vs baseline: 1.1770x; 1.1770x over previous
//
#include <hip/hip_runtime.h>

typedef _Float16 HALF;
typedef _Float16 f16x8 __attribute__((ext_vector_type(8)));
typedef float f32x4 __attribute__((ext_vector_type(4)));
typedef int i32x4 __attribute__((ext_vector_type(4)));

// ---- fused weight conversion: fp32 (27*CI, CO) -> fp16 tiled [KP/32][CO_PAD][32], zero padded
struct WArgs { const float* W[8]; HALF* dst[8]; };

__global__ void convert_all_w_kernel(WArgs a)
{
    const int CIs[8]  = {64, 64, 64, 64, 32, 32, 16, 16};
    const int COs[8]  = {64, 64, 64, 32, 32, 16, 16, 3};
    const int COPs[8] = {64, 64, 64, 32, 32, 16, 16, 16};
    const int L = blockIdx.y;
    const int CI = CIs[L], CO = COs[L], COP = COPs[L];
    const int K = 27 * CI, KP = (K + 31) & ~31;
    const int total = COP * KP;
    for (int i = blockIdx.x * 256 + threadIdx.x; i < total; i += gridDim.x * 256) {
        int jp = i / KP;          // out channel (padded)
        int kp = i - jp * KP;     // k (padded)
        float v = (jp < CO && kp < K) ? a.W[L][(size_t)kp * CO + jp] : 0.f;
        a.dst[L][((size_t)(kp >> 5) * COP + jp) * 32 + (kp & 31)] = (HALF)v;
    }
}

__global__ void convert_x_kernel(const float* __restrict__ x, HALF* __restrict__ xh, int total)
{
    int i = blockIdx.x * 256 + threadIdx.x;
    if (i < total) xh[i] = (HALF)x[i];
}

// ================= conv_static: R13 merged-tap kernel, ring deepened to 3 =================
// k-split across 4 waves by tap (7/wave); both 64B halves of each row's 128B line
// loaded adjacently; 3-deep rolling prefetch (R13's named next lever: 12 A-loads
// in flight/wave vs 8; VGPR ~92 under the (256,2) cap); in-kernel bn_prep;
// LDS tree-reduce. Used for m4/i4/m3. SEPARATE kernel from conv_dyn (R12/R13:
// co-compiled paths couple regalloc, -12%).
template<int CO_PAD, bool FUSED>
__global__ __launch_bounds__(256, 2) void conv_static(
    const HALF* __restrict__ h, const int* __restrict__ nbr,
    const HALF* __restrict__ Wt, HALF* __restrict__ yout,
    float* __restrict__ sums, int n,
    const float* __restrict__ psums, const float* __restrict__ pg,
    const float* __restrict__ pb, float pinvn)
{
    constexpr int CI   = 64;
    constexpr int NMT  = 2;
    constexpr int NJB  = CO_PAD / 16;
    constexpr int NCB  = 2;
    constexpr int ROWS = 32;
    constexpr int PAIRS = NMT * NJB;
    constexpr int TPW  = 7;
    constexpr int PD   = 3;                       // prefetch ring depth

    __shared__ f32x4 lred[2][PAIRS * 64];
    __shared__ float lscbi[2][64];

    const int wv   = threadIdx.x >> 6;
    const int lane = threadIdx.x & 63;
    const int l15  = lane & 15;
    const int lq   = lane >> 4;

    int bid = blockIdx.x;
    {
        const int nwg = gridDim.x;
        const int q = nwg >> 3, r = nwg & 7;
        const int xcd = bid & 7, idx = bid >> 3;
        bid = (xcd < r ? xcd * (q + 1) : r * (q + 1) + (xcd - r) * q) + idx;
    }
    const int rowBase = bid * ROWS;

    if constexpr (FUSED) {
        const int c = threadIdx.x;
        if (c < CI) {
            float s = 0.f, q = 0.f;
#pragma unroll
            for (int k = 0; k < 8; ++k) { s += psums[k * 128 + c]; q += psums[k * 128 + CI + c]; }
            const float mu  = s * pinvn;
            const float var = q * pinvn - mu * mu;
            const float sc  = rsqrtf(var + 1e-3f) * pg[c];
            lscbi[0][c] = sc;
            lscbi[1][c] = pb[c] - mu * sc;
        }
    }

    f32x4 acc[NMT][NJB];
#pragma unroll
    for (int mt = 0; mt < NMT; ++mt)
#pragma unroll
        for (int jb = 0; jb < NJB; ++jb)
#pragma unroll
            for (int r = 0; r < 4; ++r) acc[mt][jb][r] = 0.f;

    int  nbo[NMT];
    bool rok[NMT];
#pragma unroll
    for (int mt = 0; mt < NMT; ++mt) {
        const int row = rowBase + mt * 16 + l15;
        rok[mt] = row < n;
        nbo[mt] = min(row, n - 1) * 27;
    }

    if constexpr (FUSED) __syncthreads();

    f16x8 sc8[NCB], bi8[NCB];
    if constexpr (FUSED) {
#pragma unroll
        for (int cb = 0; cb < NCB; ++cb) {
            const int c0 = cb * 32 + ((lq * 8) & (CI - 1));
#pragma unroll
            for (int j = 0; j < 8; ++j) {
                sc8[cb][j] = (HALF)lscbi[0][c0 + j];
                bi8[cb][j] = (HALF)lscbi[1][c0 + j];
            }
        }
    }

    const int t0 = wv * TPW;

    int   ipf[PD][NMT];
    f16x8 apf[PD][NMT][2];
#pragma unroll
    for (int p = 0; p < PD; ++p) {
        const int t = t0 + p;
#pragma unroll
        for (int mt = 0; mt < NMT; ++mt) {
            const int v   = nbr[nbo[mt] + (t < 27 ? t : 26)];
            const int idx = (rok[mt] && t < 27) ? v : -1;
            ipf[p][mt] = idx;
            const HALF* pa = h + ((max(idx, 0) << 6) + lq * 8);
            apf[p][mt][0] = *(const f16x8*)(pa);
            apf[p][mt][1] = *(const f16x8*)(pa + 32);
        }
    }

#pragma unroll
    for (int tt = 0; tt < TPW; ++tt) {
        const int t = t0 + tt;
        if (t >= 27) break;                       // wave-uniform (wave3 tail)
        const int cur = tt % PD;                  // compile-time after unroll

        f16x8 a0[NMT], a1[NMT]; int im[NMT];
#pragma unroll
        for (int mt = 0; mt < NMT; ++mt) {
            a0[mt] = apf[cur][mt][0]; a1[mt] = apf[cur][mt][1]; im[mt] = ipf[cur][mt];
        }

        if (tt + PD < TPW && t + PD < 27) {
#pragma unroll
            for (int mt = 0; mt < NMT; ++mt) {
                const int v   = nbr[nbo[mt] + t + PD];
                const int idx = rok[mt] ? v : -1;
                ipf[cur][mt] = idx;
                const HALF* pa = h + ((max(idx, 0) << 6) + lq * 8);
                apf[cur][mt][0] = *(const f16x8*)(pa);
                apf[cur][mt][1] = *(const f16x8*)(pa + 32);
            }
        }

        const HALF* wb = Wt + (size_t)(2 * t) * (CO_PAD * 32) + lq * 8;
        f16x8 b0[NJB], b1[NJB];
#pragma unroll
        for (int jb = 0; jb < NJB; ++jb) {
            b0[jb] = *(const f16x8*)(wb + (size_t)(jb * 16 + l15) * 32);
            b1[jb] = *(const f16x8*)(wb + CO_PAD * 32 + (size_t)(jb * 16 + l15) * 32);
        }

#pragma unroll
        for (int mt = 0; mt < NMT; ++mt) {
            f16x8 a = a0[mt];
            if constexpr (FUSED) {
                a = a * sc8[0] + bi8[0];
#pragma unroll
                for (int j = 0; j < 8; ++j) a[j] = (a[j] < (HALF)0.f) ? (HALF)0.f : a[j];
            }
            const int m = ~(im[mt] >> 31);
            i32x4 ai = __builtin_bit_cast(i32x4, a);
            ai.x &= m; ai.y &= m; ai.z &= m; ai.w &= m;
            a = __builtin_bit_cast(f16x8, ai);
#pragma unroll
            for (int jb = 0; jb < NJB; ++jb)
                acc[mt][jb] = __builtin_amdgcn_mfma_f32_16x16x32_f16(a, b0[jb], acc[mt][jb], 0, 0, 0);
        }
#pragma unroll
        for (int mt = 0; mt < NMT; ++mt) {
            f16x8 a = a1[mt];
            if constexpr (FUSED) {
                a = a * sc8[1] + bi8[1];
#pragma unroll
                for (int j = 0; j < 8; ++j) a[j] = (a[j] < (HALF)0.f) ? (HALF)0.f : a[j];
            }
            const int m = ~(im[mt] >> 31);
            i32x4 ai = __builtin_bit_cast(i32x4, a);
            ai.x &= m; ai.y &= m; ai.z &= m; ai.w &= m;
            a = __builtin_bit_cast(f16x8, ai);
#pragma unroll
            for (int jb = 0; jb < NJB; ++jb)
                acc[mt][jb] = __builtin_amdgcn_mfma_f32_16x16x32_f16(a, b1[jb], acc[mt][jb], 0, 0, 0);
        }
    }

    // ---- cross-wave tree reduction (3 syncs)
    if (wv & 1) {
#pragma unroll
        for (int mt = 0; mt < NMT; ++mt)
#pragma unroll
            for (int jb = 0; jb < NJB; ++jb)
                lred[wv >> 1][(mt * NJB + jb) * 64 + lane] = acc[mt][jb];
    }
    __syncthreads();
    if (!(wv & 1)) {
#pragma unroll
        for (int mt = 0; mt < NMT; ++mt)
#pragma unroll
            for (int jb = 0; jb < NJB; ++jb)
                acc[mt][jb] += lred[wv >> 1][(mt * NJB + jb) * 64 + lane];
    }
    __syncthreads();
    if (wv == 2) {
#pragma unroll
        for (int mt = 0; mt < NMT; ++mt)
#pragma unroll
            for (int jb = 0; jb < NJB; ++jb)
                lred[0][(mt * NJB + jb) * 64 + lane] = acc[mt][jb];
    }
    __syncthreads();

    if (wv == 0) {
#pragma unroll
        for (int mt = 0; mt < NMT; ++mt)
#pragma unroll
            for (int jb = 0; jb < NJB; ++jb)
                acc[mt][jb] += lred[0][(mt * NJB + jb) * 64 + lane];

        float* sl = sums + (bid & 7) * 128;
#pragma unroll
        for (int jb = 0; jb < NJB; ++jb) {
            const int col = jb * 16 + l15;
            float s = 0.f, sq = 0.f;
#pragma unroll
            for (int mt = 0; mt < NMT; ++mt) {
                const int rb = rowBase + mt * 16 + lq * 4;
#pragma unroll
                for (int r = 0; r < 4; ++r) {
                    if (rb + r < n) {
                        const float v = acc[mt][jb][r];
                        yout[(size_t)(rb + r) * CO_PAD + col] = (HALF)v;
                        s += v;
                        sq += v * v;
                    }
                }
            }
            s  += __shfl_xor(s, 16);  s  += __shfl_xor(s, 32);
            sq += __shfl_xor(sq, 16); sq += __shfl_xor(sq, 32);
            if (lane < 16) {
                atomicAdd(&sl[col], s);
                atomicAdd(&sl[CO_PAD + col], sq);
            }
        }
    }
}

// ================= conv_dyn: compact-active-tap kernel (sparse layers) =================
// Voxel sparsity makes most taps all-invalid per 32-row block (exact-zero masked)
// -> skip them. Used for i3/m2/i2/m1/c5.
template<int CI, int CO_PAD, bool FUSED>
__global__ __launch_bounds__(256, 2) void conv_dyn(
    const HALF* __restrict__ h, const int* __restrict__ nbr,
    const HALF* __restrict__ Wt, HALF* __restrict__ yout,
    float* __restrict__ sums, int n,
    const float* __restrict__ psums, const float* __restrict__ pg,
    const float* __restrict__ pb, float pinvn)
{
    constexpr int NMT   = 2;
    constexpr int NJB   = CO_PAD / 16;
    constexpr int NCB   = (CI >= 64) ? 2 : 1;
    constexpr int ROWS  = 32;
    constexpr int PAIRS = NMT * NJB;

    __shared__ f32x4 lred[2][PAIRS * 64];
    __shared__ float lscbi[2][64];
    __shared__ int   lidx[ROWS * 27];
    __shared__ int   tflag[27];
    __shared__ int   tls[32];
    __shared__ int   ntapS;

    const int wv   = threadIdx.x >> 6;
    const int lane = threadIdx.x & 63;
    const int l15  = lane & 15;
    const int lq   = lane >> 4;

    int bid = blockIdx.x;
    {
        const int nwg = gridDim.x;
        const int q = nwg >> 3, r = nwg & 7;
        const int xcd = bid & 7, idx = bid >> 3;
        bid = (xcd < r ? xcd * (q + 1) : r * (q + 1) + (xcd - r) * q) + idx;
    }
    const int rowBase = bid * ROWS;

    for (int i = threadIdx.x; i < ROWS * 27; i += 256) {
        const int r   = i / 27;
        const int row = rowBase + r;
        lidx[i] = (row < n) ? nbr[(size_t)row * 27 + (i - r * 27)] : -1;
    }
    if constexpr (FUSED) {
        const int c = threadIdx.x;
        if (c < CI) {
            float s = 0.f, q = 0.f;
#pragma unroll
            for (int k = 0; k < 8; ++k) { s += psums[k * 128 + c]; q += psums[k * 128 + CI + c]; }
            const float mu  = s * pinvn;
            const float var = q * pinvn - mu * mu;
            const float sc  = rsqrtf(var + 1e-3f) * pg[c];
            lscbi[0][c] = sc;
            lscbi[1][c] = pb[c] - mu * sc;
        }
    }
    __syncthreads();

    if (threadIdx.x < 27) {
        int any = 0;
        for (int r = 0; r < ROWS; ++r) any |= ~(lidx[r * 27 + threadIdx.x] >> 31);
        tflag[threadIdx.x] = any & 1;
    }
    __syncthreads();
    if (threadIdx.x == 0) {
        int c = 0;
#pragma unroll
        for (int t = 0; t < 27; ++t) if (tflag[t]) tls[c++] = t;
        ntapS = c;
        for (int t = c; t < 32; ++t) tls[t] = 27;  // sentinel pad
    }
    __syncthreads();
    const int NT = ntapS;

    f16x8 sc8[NCB], bi8[NCB];
    if constexpr (FUSED) {
#pragma unroll
        for (int cb = 0; cb < NCB; ++cb) {
            const int c0 = cb * 32 + ((lq * 8) & (CI - 1));
#pragma unroll
            for (int j = 0; j < 8; ++j) {
                sc8[cb][j] = (HALF)lscbi[0][c0 + j];
                bi8[cb][j] = (HALF)lscbi[1][c0 + j];
            }
        }
    }

    f32x4 acc[NMT][NJB];
#pragma unroll
    for (int mt = 0; mt < NMT; ++mt)
#pragma unroll
        for (int jb = 0; jb < NJB; ++jb)
#pragma unroll
            for (int r = 0; r < 4; ++r) acc[mt][jb][r] = 0.f;

    int lb[NMT];
#pragma unroll
    for (int mt = 0; mt < NMT; ++mt) lb[mt] = (mt * 16 + l15) * 27;

    #define CONSUME(aV_, imV_, bV_, CBIDX_) do { \
        f16x8 a_ = (aV_); \
        if constexpr (FUSED) { \
            a_ = a_ * sc8[CBIDX_] + bi8[CBIDX_]; \
            _Pragma("unroll") \
            for (int j_ = 0; j_ < 8; ++j_) a_[j_] = (a_[j_] < (HALF)0.f) ? (HALF)0.f : a_[j_]; \
        } \
        const int m_ = ~((imV_) >> 31); \
        i32x4 ai_ = __builtin_bit_cast(i32x4, a_); \
        ai_.x &= m_; ai_.y &= m_; ai_.z &= m_; ai_.w &= m_; \
        a_ = __builtin_bit_cast(f16x8, ai_); \
        _Pragma("unroll") \
        for (int jb_ = 0; jb_ < NJB; ++jb_) \
            acc[mt][jb_] = __builtin_amdgcn_mfma_f32_16x16x32_f16(a_, (bV_)[jb_], acc[mt][jb_], 0, 0, 0); \
    } while (0)

    if constexpr (CI == 64) {
        int ti = wv;
        int   tcur, icur[NMT];
        f16x8 a0c[NMT], a1c[NMT];
        {
            tcur = tls[ti];
#pragma unroll
            for (int mt = 0; mt < NMT; ++mt) {
                const int idx = (tcur < 27) ? lidx[lb[mt] + min(tcur, 26)] : -1;
                icur[mt] = idx;
                const HALF* pa = h + ((max(idx, 0) << 6) + lq * 8);
                a0c[mt] = *(const f16x8*)(pa);
                a1c[mt] = *(const f16x8*)(pa + 32);
            }
        }
        for (; ti < NT; ti += 4) {
            int   tnx = tls[min(ti + 4, 31)];
            int   inx[NMT];
            f16x8 a0n[NMT], a1n[NMT];
#pragma unroll
            for (int mt = 0; mt < NMT; ++mt) {
                const int idx = (tnx < 27) ? lidx[lb[mt] + min(tnx, 26)] : -1;
                inx[mt] = idx;
                const HALF* pa = h + ((max(idx, 0) << 6) + lq * 8);
                a0n[mt] = *(const f16x8*)(pa);
                a1n[mt] = *(const f16x8*)(pa + 32);
            }

            const HALF* wb = Wt + (size_t)(2 * tcur) * (CO_PAD * 32) + lq * 8;
            f16x8 b0[NJB], b1[NJB];
#pragma unroll
            for (int jb = 0; jb < NJB; ++jb) {
                b0[jb] = *(const f16x8*)(wb + (size_t)(jb * 16 + l15) * 32);
                b1[jb] = *(const f16x8*)(wb + CO_PAD * 32 + (size_t)(jb * 16 + l15) * 32);
            }

#pragma unroll
            for (int mt = 0; mt < NMT; ++mt) CONSUME(a0c[mt], icur[mt], b0, 0);
#pragma unroll
            for (int mt = 0; mt < NMT; ++mt) CONSUME(a1c[mt], icur[mt], b1, NCB - 1);

            tcur = tnx;
#pragma unroll
            for (int mt = 0; mt < NMT; ++mt) {
                icur[mt] = inx[mt]; a0c[mt] = a0n[mt]; a1c[mt] = a1n[mt];
            }
        }
    } else if constexpr (CI == 32) {
        int ti = wv;
        int   tcur, icur[NMT];
        f16x8 ac[NMT];
        {
            tcur = tls[ti];
#pragma unroll
            for (int mt = 0; mt < NMT; ++mt) {
                const int idx = (tcur < 27) ? lidx[lb[mt] + min(tcur, 26)] : -1;
                icur[mt] = idx;
                ac[mt] = *(const f16x8*)(h + ((max(idx, 0) << 5) + lq * 8));
            }
        }
        for (; ti < NT; ti += 4) {
            int   tnx = tls[min(ti + 4, 31)];
            int   inx[NMT];
            f16x8 an[NMT];
#pragma unroll
            for (int mt = 0; mt < NMT; ++mt) {
                const int idx = (tnx < 27) ? lidx[lb[mt] + min(tnx, 26)] : -1;
                inx[mt] = idx;
                an[mt] = *(const f16x8*)(h + ((max(idx, 0) << 5) + lq * 8));
            }

            const HALF* wb = Wt + (size_t)tcur * (CO_PAD * 32) + lq * 8;
            f16x8 b[NJB];
#pragma unroll
            for (int jb = 0; jb < NJB; ++jb)
                b[jb] = *(const f16x8*)(wb + (size_t)(jb * 16 + l15) * 32);

#pragma unroll
            for (int mt = 0; mt < NMT; ++mt) CONSUME(ac[mt], icur[mt], b, 0);

            tcur = tnx;
#pragma unroll
            for (int mt = 0; mt < NMT; ++mt) { icur[mt] = inx[mt]; ac[mt] = an[mt]; }
        }
    } else {
        // CI == 16: two list entries per MFMA step (lq>>1 selects); sentinel masked
        const int NS = (NT + 1) >> 1;
        int ti = wv;
        int   tcur, icur[NMT];
        f16x8 ac[NMT];
        {
            tcur = tls[min(2 * ti + (lq >> 1), 31)];
#pragma unroll
            for (int mt = 0; mt < NMT; ++mt) {
                const int idx = (tcur < 27) ? lidx[lb[mt] + min(tcur, 26)] : -1;
                icur[mt] = idx;
                ac[mt] = *(const f16x8*)(h + ((max(idx, 0) << 4) + (lq & 1) * 8));
            }
        }
        for (; ti < NS; ti += 4) {
            int   tnx = tls[min(2 * (ti + 4) + (lq >> 1), 31)];
            int   inx[NMT];
            f16x8 an[NMT];
#pragma unroll
            for (int mt = 0; mt < NMT; ++mt) {
                const int idx = (tnx < 27) ? lidx[lb[mt] + min(tnx, 26)] : -1;
                inx[mt] = idx;
                an[mt] = *(const f16x8*)(h + ((max(idx, 0) << 4) + (lq & 1) * 8));
            }

            const int tb = min(tcur, 26);
            f16x8 b[NJB];
#pragma unroll
            for (int jb = 0; jb < NJB; ++jb)
                b[jb] = *(const f16x8*)(Wt + (size_t)(tb >> 1) * (CO_PAD * 32)
                                        + (size_t)(jb * 16 + l15) * 32 + (tb & 1) * 16 + (lq & 1) * 8);

#pragma unroll
            for (int mt = 0; mt < NMT; ++mt) CONSUME(ac[mt], icur[mt], b, 0);

            tcur = tnx;
#pragma unroll
            for (int mt = 0; mt < NMT; ++mt) { icur[mt] = inx[mt]; ac[mt] = an[mt]; }
        }
    }
    #undef CONSUME

    // ---- cross-wave tree reduction (3 syncs)
    if (wv & 1) {
#pragma unroll
        for (int mt = 0; mt < NMT; ++mt)
#pragma unroll
            for (int jb = 0; jb < NJB; ++jb)
                lred[wv >> 1][(mt * NJB + jb) * 64 + lane] = acc[mt][jb];
    }
    __syncthreads();
    if (!(wv & 1)) {
#pragma unroll
        for (int mt = 0; mt < NMT; ++mt)
#pragma unroll
            for (int jb = 0; jb < NJB; ++jb)
                acc[mt][jb] += lred[wv >> 1][(mt * NJB + jb) * 64 + lane];
    }
    __syncthreads();
    if (wv == 2) {
#pragma unroll
        for (int mt = 0; mt < NMT; ++mt)
#pragma unroll
            for (int jb = 0; jb < NJB; ++jb)
                lred[0][(mt * NJB + jb) * 64 + lane] = acc[mt][jb];
    }
    __syncthreads();

    if (wv == 0) {
#pragma unroll
        for (int mt = 0; mt < NMT; ++mt)
#pragma unroll
            for (int jb = 0; jb < NJB; ++jb)
                acc[mt][jb] += lred[0][(mt * NJB + jb) * 64 + lane];

        float* sl = sums + (bid & 7) * 128;
#pragma unroll
        for (int jb = 0; jb < NJB; ++jb) {
            const int col = jb * 16 + l15;
            float s = 0.f, sq = 0.f;
#pragma unroll
            for (int mt = 0; mt < NMT; ++mt) {
                const int rb = rowBase + mt * 16 + lq * 4;
#pragma unroll
                for (int r = 0; r < 4; ++r) {
                    if (rb + r < n) {
                        const float v = acc[mt][jb][r];
                        yout[(size_t)(rb + r) * CO_PAD + col] = (HALF)v;
                        s += v;
                        sq += v * v;
                    }
                }
            }
            s  += __shfl_xor(s, 16);  s  += __shfl_xor(s, 32);
            sq += __shfl_xor(sq, 16); sq += __shfl_xor(sq, 32);
            if (lane < 16) {
                atomicAdd(&sl[col], s);
                atomicAdd(&sl[CO_PAD + col], sq);
            }
        }
    }
}

// ---- final: normalize (no relu), co=3 out of CO_PAD=16, fp32 output; striped sums
__global__ void bn_out_kernel(const HALF* __restrict__ y, const float* __restrict__ sums,
                              const float* __restrict__ g, const float* __restrict__ b,
                              int n, float invn, float* __restrict__ out)
{
    int i = blockIdx.x * 256 + threadIdx.x;
    if (i >= n * 3) return;
    int row = i / 3;
    int c = i - row * 3;
    float ssum = 0.f, qsum = 0.f;
#pragma unroll
    for (int k2 = 0; k2 < 8; ++k2) {
        ssum += sums[k2 * 128 + c];
        qsum += sums[k2 * 128 + 16 + c];
    }
    float mu  = ssum * invn;
    float var = qsum * invn - mu * mu;
    float sc  = rsqrtf(var + 1e-3f) * g[c];
    out[i] = ((float)y[(size_t)row * 16 + c] - mu) * sc + b[c];
}

extern "C" void kernel_launch(void* const* d_in, const int* in_sizes, int n_in,
                              void* d_out, int out_size, void* d_ws, size_t ws_size,
                              hipStream_t stream)
{
    const int* nbr4  = (const int*)d_in[0];
    const int* inv43 = (const int*)d_in[1];
    const int* nbr3  = (const int*)d_in[2];
    const int* inv32 = (const int*)d_in[3];
    const int* nbr2  = (const int*)d_in[4];
    const int* inv21 = (const int*)d_in[5];
    const int* nbr1  = (const int*)d_in[6];
    const float* x   = (const float*)d_in[7];

    const int n4 = in_sizes[0] / 27;
    const int n3 = in_sizes[1] / 27;
    const int n2 = in_sizes[3] / 27;
    const int n1 = in_sizes[5] / 27;

    // specs: m4,i4,m3,i3,m2,i2,m1,c5
    const int CIs[8]  = {64, 64, 64, 64, 32, 32, 16, 16};
    const int COPs[8] = {64, 64, 64, 32, 32, 16, 16, 16};
    int KPs[8], wtoff[8];
    int wtot = 0;
    for (int s = 0; s < 8; ++s) {
        KPs[s] = ((27 * CIs[s] + 31) / 32) * 32;
        wtoff[s] = wtot;
        wtot += COPs[s] * KPs[s];
    }

    char* ws = (char*)d_ws;
    HALF* wt = (HALF*)ws;
    size_t off = ((size_t)wtot * sizeof(HALF) + 255) & ~(size_t)255;
    float* sums = (float*)(ws + off);
    off += 8 * 1024 * sizeof(float);              // 8 layers x 8 stripes x 128 floats
    off = (off + 255) & ~(size_t)255;
    HALF* xh = (HALF*)(ws + off);
    off += ((size_t)n4 * 64 * sizeof(HALF) + 255) & ~(size_t)255;
    size_t bufElems = 0;
    {
        size_t cand[4] = {(size_t)n4 * 64, (size_t)n3 * 64, (size_t)n2 * 32, (size_t)n1 * 16};
        for (int i = 0; i < 4; ++i) if (cand[i] > bufElems) bufElems = cand[i];
    }
    HALF* Y0 = (HALF*)(ws + off);
    off += (bufElems * sizeof(HALF) + 255) & ~(size_t)255;
    HALF* Y1 = (HALF*)(ws + off);

    hipMemsetAsync(sums, 0, 8 * 1024 * sizeof(float), stream);

    WArgs wa;
    for (int s = 0; s < 8; ++s) { wa.W[s] = (const float*)d_in[8 + 3 * s]; wa.dst[s] = wt + wtoff[s]; }
    {
        int maxTotal = 64 * KPs[0];
        dim3 grid((maxTotal + 255) / 256, 8);
        convert_all_w_kernel<<<grid, 256, 0, stream>>>(wa);
    }
    convert_x_kernel<<<(n4 * 64 + 255) / 256, 256, 0, stream>>>(x, xh, n4 * 64);

#define G(s) ((const float*)d_in[9 + 3 * (s)])
#define B(s) ((const float*)d_in[10 + 3 * (s)])
#define SUMS(s) (sums + (s) * 1024)
#define GRID(nn) (((nn) + 31) / 32)

    // m4: xh(n4,64) -> Y0 (raw)  [static]
    conv_static<64, false><<<GRID(n4), 256, 0, stream>>>(
        xh, nbr4, wt + wtoff[0], Y0, SUMS(0), n4, nullptr, nullptr, nullptr, 0.f);
    // i4: norm(m4) fused; Y0(n4) -> Y1(n3)  [static]
    conv_static<64, true><<<GRID(n3), 256, 0, stream>>>(
        Y0, inv43, wt + wtoff[1], Y1, SUMS(1), n3, SUMS(0), G(0), B(0), 1.f / n4);
    // m3: norm(i4) fused; Y1 -> Y0  [static]
    conv_static<64, true><<<GRID(n3), 256, 0, stream>>>(
        Y1, nbr3, wt + wtoff[2], Y0, SUMS(2), n3, SUMS(1), G(1), B(1), 1.f / n3);
    // i3: norm(m3) fused; Y0(n3) -> Y1(n2), co 32  [dynamic]
    conv_dyn<64, 32, true><<<GRID(n2), 256, 0, stream>>>(
        Y0, inv32, wt + wtoff[3], Y1, SUMS(3), n2, SUMS(2), G(2), B(2), 1.f / n3);
    // m2: norm(i3) fused; Y1 -> Y0  [dynamic]
    conv_dyn<32, 32, true><<<GRID(n2), 256, 0, stream>>>(
        Y1, nbr2, wt + wtoff[4], Y0, SUMS(4), n2, SUMS(3), G(3), B(3), 1.f / n2);
    // i2: norm(m2) fused; Y0(n2) -> Y1(n1), co 16  [dynamic]
    conv_dyn<32, 16, true><<<GRID(n1), 256, 0, stream>>>(
        Y0, inv21, wt + wtoff[5], Y1, SUMS(5), n1, SUMS(4), G(4), B(4), 1.f / n2);
    // m1: norm(i2) fused; Y1 -> Y0  [dynamic]
    conv_dyn<16, 16, true><<<GRID(n1), 256, 0, stream>>>(
        Y1, nbr1, wt + wtoff[6], Y0, SUMS(6), n1, SUMS(5), G(5), B(5), 1.f / n1);
    // c5: norm(m1) fused; Y0 -> Y1 (raw), then fp32 out  [dynamic]
    conv_dyn<16, 16, true><<<GRID(n1), 256, 0, stream>>>(
        Y0, nbr1, wt + wtoff[7], Y1, SUMS(7), n1, SUMS(6), G(6), B(6), 1.f / n1);
    bn_out_kernel<<<(n1 * 3 + 255) / 256, 256, 0, stream>>>(
        Y1, SUMS(7), G(7), B(7), n1, 1.f / n1, (float*)d_out);

#undef G
#undef B
#undef SUMS
#undef GRID
}